// Round 1
// baseline (641.687 us; speedup 1.0000x reference)
//
#include <hip/hip_runtime.h>
#include <cstddef>

// Problem constants
constexpr int Bn  = 512;
constexpr int Dd  = 960;
constexpr int RL  = 16;
constexpr int RD  = 32;
constexpr int LPp = 16;
constexpr int LHh = 384;
constexpr int DP  = 358;
constexpr int DH  = 154;

// =====================================================================
// proj: Y[m, r] = (mask[m] ? X[m, :] : 0) @ Bc[:, r]
// X: (M, 960) f32 (rows flattened over batch*L), mask: (M) int32,
// Bc: (960, 32), Y: (M, 32).  M % 128 == 0.
// Fully-masked 128-row tiles: zero-fill Y and early-exit (saves HBM+FMA).
// =====================================================================
__global__ __launch_bounds__(256)
void proj_kernel(const float* __restrict__ X, const int* __restrict__ mask,
                 const float* __restrict__ Bc, float* __restrict__ Y)
{
    constexpr int TL = 128, KC = 32, PITCH = TL + 4; // pitch 132 (mult of 4 -> aligned b128)
    __shared__ float XsT[KC][PITCH];   // transposed X chunk: [k][row]
    __shared__ float Bs[KC][RD];
    __shared__ int   msk[TL];
    __shared__ int   s_any;
    const int t = threadIdx.x;
    const size_t m0 = (size_t)blockIdx.x * TL;

    if (t == 0) s_any = 0;
    if (t < TL) msk[t] = mask[m0 + t];
    __syncthreads();
    if (t < TL && msk[t]) s_any = 1;
    __syncthreads();
    if (s_any == 0) {
        // whole tile masked -> Y rows are exactly zero
        float4 z4 = make_float4(0.f, 0.f, 0.f, 0.f);
        for (int i = t; i < TL * RD / 4; i += 256)
            *(float4*)&Y[m0 * RD + (size_t)i * 4] = z4;
        return;
    }

    const int r0 = (t >> 3) << 2;  // 0..124
    const int c0 = (t & 7) << 2;   // 0..28
    float acc[4][4] = {};

    for (int k0 = 0; k0 < Dd; k0 += KC) {   // 30 chunks
        // stage X^T (128 rows x 32 k), masked rows -> 0 (also skips the load)
        #pragma unroll
        for (int j = 0; j < 4; ++j) {
            int idx = t + j * 256;
            int row = idx >> 3, c4 = idx & 7;
            float4 v = make_float4(0.f, 0.f, 0.f, 0.f);
            if (msk[row])
                v = *(const float4*)&X[(m0 + row) * (size_t)Dd + k0 + c4 * 4];
            XsT[c4 * 4 + 0][row] = v.x;
            XsT[c4 * 4 + 1][row] = v.y;
            XsT[c4 * 4 + 2][row] = v.z;
            XsT[c4 * 4 + 3][row] = v.w;
        }
        // stage Bc chunk (32 x 32)
        {
            int kk = t >> 3, c4 = t & 7;
            *(float4*)&Bs[kk][c4 * 4] =
                *(const float4*)&Bc[(size_t)(k0 + kk) * RD + c4 * 4];
        }
        __syncthreads();
        #pragma unroll
        for (int kk = 0; kk < KC; ++kk) {
            float4 av = *(const float4*)&XsT[kk][r0];
            float4 wv = *(const float4*)&Bs[kk][c0];
            const float a[4] = {av.x, av.y, av.z, av.w};
            const float w[4] = {wv.x, wv.y, wv.z, wv.w};
            #pragma unroll
            for (int i = 0; i < 4; ++i)
                #pragma unroll
                for (int j = 0; j < 4; ++j)
                    acc[i][j] = fmaf(a[i], w[j], acc[i][j]);
        }
        __syncthreads();
    }
    #pragma unroll
    for (int i = 0; i < 4; ++i) {
        float4 v = make_float4(acc[i][0], acc[i][1], acc[i][2], acc[i][3]);
        *(float4*)&Y[(m0 + r0 + i) * RD + c0] = v;
    }
}

// =====================================================================
// uz: per-batch  U[p,r] = sum_l A[l,p] * Y[b,l,r];  z[b,j] = sum_i U.flat[i]*Hc[i,j]
// Y: (B*L, 32), A: (L, 16), Hc: (512, dmod), z: (B, dmod)
// =====================================================================
__global__ __launch_bounds__(256)
void uz_kernel(const float* __restrict__ Y, const float* __restrict__ A,
               const float* __restrict__ Hc, float* __restrict__ z,
               int L, int dmod)
{
    constexpr int LC = 128;
    __shared__ float Ys[LC][33];
    __shared__ float As[LC][17];
    __shared__ float Ush[RL * RD]; // 512
    const int t = threadIdx.x;
    const int b = blockIdx.x;
    const int p = t >> 5, r = t & 31;
    float u0 = 0.f, u1 = 0.f;

    for (int l0 = 0; l0 < L; l0 += LC) {
        const int rows = min(LC, L - l0);
        for (int i = t; i < rows * RD; i += 256) {
            int lr = i >> 5, c = i & 31;
            Ys[lr][c] = Y[((size_t)b * L + l0 + lr) * RD + c];
        }
        for (int i = t; i < rows * RL; i += 256) {
            int lr = i >> 4, pp = i & 15;
            As[lr][pp] = A[(size_t)(l0 + lr) * RL + pp];
        }
        __syncthreads();
        for (int l = 0; l < rows; ++l) {
            float yv = Ys[l][r];
            u0 = fmaf(As[l][p], yv, u0);
            u1 = fmaf(As[l][p + 8], yv, u1);
        }
        __syncthreads();
    }
    Ush[t]       = u0;  // flat index p*32+r   (p in 0..7)
    Ush[t + 256] = u1;  // flat index (p+8)*32+r
    __syncthreads();

    for (int j = t; j < dmod; j += 256) {
        float acc = 0.f;
        #pragma unroll 8
        for (int i = 0; i < RL * RD; ++i)
            acc = fmaf(Ush[i], Hc[(size_t)i * dmod + j], acc);
        z[(size_t)b * dmod + j] = acc;
    }
}

// =====================================================================
// mlp: C = A(512,K) @ W(K,N) + bias, with epilogue:
//   MODE 0: h = relu((C)*g/sqrt(1+eps) + beta)  -> out (512,N) pitch N
//   MODE 1: C -> out[m*ostride + ooff + c]      (concat store into d_out)
// =====================================================================
template <int MODE>
__global__ __launch_bounds__(256)
void mlp_kernel(const float* __restrict__ Aa, const float* __restrict__ W,
                const float* __restrict__ bias, const float* __restrict__ g,
                const float* __restrict__ beta, float* __restrict__ out,
                int K, int N, int ooff, int ostride)
{
    constexpr int TM = 64, TN = 64, KC = 32;
    __shared__ float AsT[KC][TM + 4]; // [k][row], pitch 68
    __shared__ float Ws[KC][TN];
    const int t = threadIdx.x;
    const int m0 = blockIdx.x * TM;
    const int n0 = blockIdx.y * TN;
    const int r0 = (t >> 4) << 2;
    const int c0 = (t & 15) << 2;
    float acc[4][4] = {};

    for (int k0 = 0; k0 < K; k0 += KC) {
        // stage A tile transposed (scalar: K pitch 358/154 not 16B-aligned)
        for (int i = t; i < TM * KC; i += 256) {
            int row = i >> 5, kk = i & 31;
            int kg = k0 + kk;
            AsT[kk][row] = (kg < K) ? Aa[(size_t)(m0 + row) * K + kg] : 0.f;
        }
        // stage W tile
        for (int i = t; i < KC * TN; i += 256) {
            int kk = i >> 6, c = i & 63;
            int kg = k0 + kk, cg = n0 + c;
            Ws[kk][c] = (kg < K && cg < N) ? W[(size_t)kg * N + cg] : 0.f;
        }
        __syncthreads();
        #pragma unroll
        for (int kk = 0; kk < KC; ++kk) {
            float4 av = *(const float4*)&AsT[kk][r0];
            float4 wv = *(const float4*)&Ws[kk][c0];
            const float a[4] = {av.x, av.y, av.z, av.w};
            const float w[4] = {wv.x, wv.y, wv.z, wv.w};
            #pragma unroll
            for (int i = 0; i < 4; ++i)
                #pragma unroll
                for (int j = 0; j < 4; ++j)
                    acc[i][j] = fmaf(a[i], w[j], acc[i][j]);
        }
        __syncthreads();
    }

    const float bscale = rsqrtf(1.f + 1e-5f);
    #pragma unroll
    for (int j = 0; j < 4; ++j) {
        int c = n0 + c0 + j;
        if (c < N) {
            float bb = bias[c];
            float gg = 0.f, be = 0.f;
            if constexpr (MODE == 0) { gg = g[c] * bscale; be = beta[c]; }
            #pragma unroll
            for (int i = 0; i < 4; ++i) {
                int m = m0 + r0 + i;
                float v = acc[i][j] + bb;
                if constexpr (MODE == 0) {
                    v = fmaf(v, gg, be);
                    v = fmaxf(v, 0.f);
                    out[(size_t)m * N + c] = v;
                } else {
                    out[(size_t)m * ostride + ooff + c] = v;
                }
            }
        }
    }
}

// =====================================================================
extern "C" void kernel_launch(void* const* d_in, const int* in_sizes, int n_in,
                              void* d_out, int out_size, void* d_ws, size_t ws_size,
                              hipStream_t stream)
{
    const float* emb_P  = (const float*)d_in[0];
    const float* emb_H  = (const float*)d_in[1];
    const int*   mask_P = (const int*)  d_in[2];
    const int*   mask_H = (const int*)  d_in[3];
    const float* B_cP   = (const float*)d_in[4];
    const float* A_cP   = (const float*)d_in[5];
    const float* H_cP   = (const float*)d_in[6];
    const float* W1P    = (const float*)d_in[7];
    const float* b1P    = (const float*)d_in[8];
    const float* gP     = (const float*)d_in[9];
    const float* betaP  = (const float*)d_in[10];
    const float* W2P    = (const float*)d_in[11];
    const float* b2P    = (const float*)d_in[12];
    const float* B_cH   = (const float*)d_in[13];
    const float* A_cH   = (const float*)d_in[14];
    const float* H_cH   = (const float*)d_in[15];
    const float* W1H    = (const float*)d_in[16];
    const float* b1H    = (const float*)d_in[17];
    const float* gH     = (const float*)d_in[18];
    const float* betaH  = (const float*)d_in[19];
    const float* W2H    = (const float*)d_in[20];
    const float* b2H    = (const float*)d_in[21];
    float* outp = (float*)d_out;

    // workspace layout (floats)
    float* ws  = (float*)d_ws;
    float* Y_P = ws;                         // 512*16*32   = 262144
    float* Y_H = Y_P + (size_t)Bn * LPp * RD; // 512*384*32 = 6291456
    float* z_P = Y_H + (size_t)Bn * LHh * RD; // 512*358    = 183296
    float* z_H = z_P + (size_t)Bn * DP;       // 512*154    = 78848
    float* h_P = z_H + (size_t)Bn * DH;       // 512*358
    float* h_H = h_P + (size_t)Bn * DP;       // 512*154

    dim3 blk(256);

    proj_kernel<<<dim3((Bn * LPp) / 128), blk, 0, stream>>>(emb_P, mask_P, B_cP, Y_P);
    proj_kernel<<<dim3((Bn * LHh) / 128), blk, 0, stream>>>(emb_H, mask_H, B_cH, Y_H);

    uz_kernel<<<dim3(Bn), blk, 0, stream>>>(Y_P, A_cP, H_cP, z_P, LPp, DP);
    uz_kernel<<<dim3(Bn), blk, 0, stream>>>(Y_H, A_cH, H_cH, z_H, LHh, DH);

    mlp_kernel<0><<<dim3(8, (DP + 63) / 64), blk, 0, stream>>>(
        z_P, W1P, b1P, gP, betaP, h_P, DP, DP, 0, 0);
    mlp_kernel<0><<<dim3(8, (DH + 63) / 64), blk, 0, stream>>>(
        z_H, W1H, b1H, gH, betaH, h_H, DH, DH, 0, 0);

    mlp_kernel<1><<<dim3(8, (DP + 63) / 64), blk, 0, stream>>>(
        h_P, W2P, b2P, nullptr, nullptr, outp, DP, DP, 0, DP + DH);
    mlp_kernel<1><<<dim3(8, (DH + 63) / 64), blk, 0, stream>>>(
        h_H, W2H, b2H, nullptr, nullptr, outp, DH, DH, DP, DP + DH);
}

// Round 2
// 453.615 us; speedup vs baseline: 1.4146x; 1.4146x over previous
//
#include <hip/hip_runtime.h>
#include <cstddef>

// Problem constants
constexpr int Bn  = 512;
constexpr int Dd  = 960;
constexpr int RL  = 16;
constexpr int RD  = 32;
constexpr int LPp = 16;
constexpr int LHh = 384;
constexpr int DP  = 358;
constexpr int DH  = 154;
constexpr int CHW = 480;   // vproj d-chunk width (threads 0..239 own 2 d each)

// =====================================================================
// K1 vproj: V[b][p][d] = sum_{l < len_b} A[l][p] * X[b][l][d]
// (reassociated low-rank projection: V = A^T Xm, 16 x 960 per batch)
// grid: [0, 2*Bn) -> H (b = id>>1, d-chunk = id&1); [2*Bn, 4*Bn) -> P
// Hot loop: coalesced float2 X stream (read-once), lane-uniform A row
// (scalar loads), 32 FMA per 8 bytes of HBM -> HBM-bound, no LDS.
// =====================================================================
__global__ __launch_bounds__(256)
void vproj_kernel(const float* __restrict__ embH, const int* __restrict__ maskH,
                  const float* __restrict__ AH, float* __restrict__ VH,
                  const float* __restrict__ embP, const int* __restrict__ maskP,
                  const float* __restrict__ AP, float* __restrict__ VP)
{
    int id = blockIdx.x;
    const float* X; const int* mask; const float* A; float* V; int L;
    if (id < 2 * Bn) { X = embH; mask = maskH; A = AH; V = VH; L = LHh; }
    else { id -= 2 * Bn; X = embP; mask = maskP; A = AP; V = VP; L = LPp; }
    const int b  = id >> 1;
    const int d0 = (id & 1) * CHW;
    const int t  = threadIdx.x;

    // len_b = sum of contiguous-prefix mask row
    __shared__ int s_len;
    if (t == 0) s_len = 0;
    __syncthreads();
    int loc = 0;
    for (int i = t; i < L; i += 256) loc += mask[(size_t)b * L + i];
    if (loc) atomicAdd(&s_len, loc);
    __syncthreads();
    const int len = s_len;

    if (t >= CHW / 2) return;   // no barriers below this point

    float v[RL][2];
    #pragma unroll
    for (int p = 0; p < RL; ++p) { v[p][0] = 0.f; v[p][1] = 0.f; }

    const float* xptr = X + (size_t)b * L * Dd + d0 + 2 * t;
    #pragma unroll 2
    for (int l = 0; l < len; ++l) {
        const float2 xv = *(const float2*)xptr;
        xptr += Dd;
        float a[RL];
        *(float4*)&a[0]  = *(const float4*)(A + (size_t)l * RL + 0);
        *(float4*)&a[4]  = *(const float4*)(A + (size_t)l * RL + 4);
        *(float4*)&a[8]  = *(const float4*)(A + (size_t)l * RL + 8);
        *(float4*)&a[12] = *(const float4*)(A + (size_t)l * RL + 12);
        #pragma unroll
        for (int p = 0; p < RL; ++p) {
            v[p][0] = fmaf(a[p], xv.x, v[p][0]);
            v[p][1] = fmaf(a[p], xv.y, v[p][1]);
        }
    }
    #pragma unroll
    for (int p = 0; p < RL; ++p)
        *(float2*)(V + ((size_t)b * RL + p) * Dd + d0 + 2 * t) =
            make_float2(v[p][0], v[p][1]);
}

// =====================================================================
// K2 uz2: per batch  U[p,r] = sum_d V[p,d] * Bc[d,r]  (16x32),
//          z[b,j]    = sum_i U.flat[i] * Hc[i,j]
// grid: [0, Bn) -> P, [Bn, 2*Bn) -> H.  V chunk-staged in LDS (15 KB);
// Bc rows come from L1 (each 128B line shared by all waves per d).
// =====================================================================
__global__ __launch_bounds__(256)
void uz2_kernel(const float* __restrict__ VP, const float* __restrict__ BcP,
                const float* __restrict__ HcP, float* __restrict__ zP,
                const float* __restrict__ VH, const float* __restrict__ BcH,
                const float* __restrict__ HcH, float* __restrict__ zH)
{
    int bid = blockIdx.x;
    const float* V; const float* Bc; const float* Hc; float* z; int dmod;
    if (bid < Bn) { V = VP; Bc = BcP; Hc = HcP; z = zP; dmod = DP; }
    else { bid -= Bn; V = VH; Bc = BcH; Hc = HcH; z = zH; dmod = DH; }
    const int b = bid, t = threadIdx.x;

    constexpr int DC = 240;
    __shared__ float Vs[RL][DC];
    __shared__ float Ush[RL * RD];
    const int p = t >> 5, r = t & 31;
    float u0 = 0.f, u1 = 0.f;

    for (int d0 = 0; d0 < Dd; d0 += DC) {
        __syncthreads();
        if (t < DC) {
            #pragma unroll
            for (int pp = 0; pp < RL; ++pp)
                Vs[pp][t] = V[((size_t)b * RL + pp) * Dd + d0 + t];
        }
        __syncthreads();
        #pragma unroll 4
        for (int dd = 0; dd < DC; ++dd) {
            float bc = Bc[(size_t)(d0 + dd) * RD + r];
            u0 = fmaf(Vs[p][dd],     bc, u0);
            u1 = fmaf(Vs[p + 8][dd], bc, u1);
        }
    }
    Ush[p * RD + r]       = u0;
    Ush[(p + 8) * RD + r] = u1;
    __syncthreads();

    for (int j = t; j < dmod; j += 256) {
        float acc = 0.f;
        #pragma unroll 8
        for (int i = 0; i < RL * RD; ++i)
            acc = fmaf(Ush[i], Hc[(size_t)i * dmod + j], acc);
        z[(size_t)b * dmod + j] = acc;
    }
}

// =====================================================================
// K3/K4 mlp2: C = A(512,K) @ W(K,N) + bias, P and H fused in one grid.
//   MODE 0: h = relu(C * g/sqrt(1+eps) + beta) -> out (512,N) pitch N
//   MODE 1: C -> d_out[m*(DP+DH) + ooff + c]   (concat store)
// grid: (8, nbP + nbH); blockIdx.y selects encoder + n-tile.
// =====================================================================
template <int MODE>
__global__ __launch_bounds__(256)
void mlp2_kernel(const float* __restrict__ AaP, const float* __restrict__ WP,
                 const float* __restrict__ biasP, const float* __restrict__ gPv,
                 const float* __restrict__ betaPv, float* __restrict__ outP,
                 const float* __restrict__ AaH, const float* __restrict__ WH,
                 const float* __restrict__ biasH, const float* __restrict__ gHv,
                 const float* __restrict__ betaHv, float* __restrict__ outH,
                 int nbP)
{
    const float *Aa, *W, *bias, *g, *beta; float* out;
    int K, N, n0, ooff;
    if ((int)blockIdx.y < nbP) {
        Aa = AaP; W = WP; bias = biasP; g = gPv; beta = betaPv; out = outP;
        K = DP; N = DP; n0 = blockIdx.y * 64; ooff = 0;
    } else {
        Aa = AaH; W = WH; bias = biasH; g = gHv; beta = betaHv; out = outH;
        K = DH; N = DH; n0 = (blockIdx.y - nbP) * 64; ooff = DP;
    }
    const int ostride = (MODE == 0) ? N : (DP + DH);
    if (MODE == 0) ooff = 0;

    constexpr int TM = 64, TN = 64, KC = 32;
    __shared__ float AsT[KC][TM + 4];
    __shared__ float Ws[KC][TN];
    const int t  = threadIdx.x;
    const int m0 = blockIdx.x * TM;
    const int r0 = (t >> 4) << 2;
    const int c0 = (t & 15) << 2;
    float acc[4][4] = {};

    for (int k0 = 0; k0 < K; k0 += KC) {
        for (int i = t; i < TM * KC; i += 256) {
            int row = i >> 5, kk = i & 31;
            int kg = k0 + kk;
            AsT[kk][row] = (kg < K) ? Aa[(size_t)(m0 + row) * K + kg] : 0.f;
        }
        for (int i = t; i < KC * TN; i += 256) {
            int kk = i >> 6, c = i & 63;
            int kg = k0 + kk, cg = n0 + c;
            Ws[kk][c] = (kg < K && cg < N) ? W[(size_t)kg * N + cg] : 0.f;
        }
        __syncthreads();
        #pragma unroll
        for (int kk = 0; kk < KC; ++kk) {
            float4 av = *(const float4*)&AsT[kk][r0];
            float4 wv = *(const float4*)&Ws[kk][c0];
            const float a[4] = {av.x, av.y, av.z, av.w};
            const float w[4] = {wv.x, wv.y, wv.z, wv.w};
            #pragma unroll
            for (int i = 0; i < 4; ++i)
                #pragma unroll
                for (int j = 0; j < 4; ++j)
                    acc[i][j] = fmaf(a[i], w[j], acc[i][j]);
        }
        __syncthreads();
    }

    const float bscale = rsqrtf(1.f + 1e-5f);
    #pragma unroll
    for (int j = 0; j < 4; ++j) {
        int c = n0 + c0 + j;
        if (c < N) {
            float bb = bias[c];
            float gg = 0.f, be = 0.f;
            if constexpr (MODE == 0) { gg = g[c] * bscale; be = beta[c]; }
            #pragma unroll
            for (int i = 0; i < 4; ++i) {
                int m = m0 + r0 + i;
                float v = acc[i][j] + bb;
                if constexpr (MODE == 0) {
                    v = fmaf(v, gg, be);
                    v = fmaxf(v, 0.f);
                    out[(size_t)m * N + c] = v;
                } else {
                    out[(size_t)m * ostride + ooff + c] = v;
                }
            }
        }
    }
}

// =====================================================================
extern "C" void kernel_launch(void* const* d_in, const int* in_sizes, int n_in,
                              void* d_out, int out_size, void* d_ws, size_t ws_size,
                              hipStream_t stream)
{
    const float* emb_P  = (const float*)d_in[0];
    const float* emb_H  = (const float*)d_in[1];
    const int*   mask_P = (const int*)  d_in[2];
    const int*   mask_H = (const int*)  d_in[3];
    const float* B_cP   = (const float*)d_in[4];
    const float* A_cP   = (const float*)d_in[5];
    const float* H_cP   = (const float*)d_in[6];
    const float* W1P    = (const float*)d_in[7];
    const float* b1P    = (const float*)d_in[8];
    const float* gP     = (const float*)d_in[9];
    const float* betaP  = (const float*)d_in[10];
    const float* W2P    = (const float*)d_in[11];
    const float* b2P    = (const float*)d_in[12];
    const float* B_cH   = (const float*)d_in[13];
    const float* A_cH   = (const float*)d_in[14];
    const float* H_cH   = (const float*)d_in[15];
    const float* W1H    = (const float*)d_in[16];
    const float* b1H    = (const float*)d_in[17];
    const float* gH     = (const float*)d_in[18];
    const float* betaH  = (const float*)d_in[19];
    const float* W2H    = (const float*)d_in[20];
    const float* b2H    = (const float*)d_in[21];
    float* outp = (float*)d_out;

    // workspace layout (floats)
    float* ws  = (float*)d_ws;
    float* V_H = ws;                              // 512*16*960 = 7864320
    float* V_P = V_H + (size_t)Bn * RL * Dd;      // 7864320
    float* z_P = V_P + (size_t)Bn * RL * Dd;      // 512*358
    float* z_H = z_P + (size_t)Bn * DP;           // 512*154
    float* h_P = z_H + (size_t)Bn * DH;           // 512*358
    float* h_H = h_P + (size_t)Bn * DP;           // 512*154

    dim3 blk(256);

    // K1: V = A^T Xm for H (2 chunks/batch) then P
    vproj_kernel<<<dim3(4 * Bn), blk, 0, stream>>>(
        emb_H, mask_H, A_cH, V_H, emb_P, mask_P, A_cP, V_P);

    // K2: U = V Bc ; z = vec(U) Hc   (P blocks first: larger dmod)
    uz2_kernel<<<dim3(2 * Bn), blk, 0, stream>>>(
        V_P, B_cP, H_cP, z_P, V_H, B_cH, H_cH, z_H);

    // K3: layer 1 (BN-scale + ReLU), P tiles y=0..5, H tiles y=6..8
    mlp2_kernel<0><<<dim3(8, 9), blk, 0, stream>>>(
        z_P, W1P, b1P, gP, betaP, h_P,
        z_H, W1H, b1H, gH, betaH, h_H, 6);

    // K4: layer 2 + concat store into d_out
    mlp2_kernel<1><<<dim3(8, 9), blk, 0, stream>>>(
        h_P, W2P, b2P, nullptr, nullptr, outp,
        h_H, W2H, b2H, nullptr, nullptr, outp, 6);
}

// Round 3
// 249.200 us; speedup vs baseline: 2.5750x; 1.8203x over previous
//
#include <hip/hip_runtime.h>
#include <cstddef>

// Problem constants
constexpr int Bn  = 512;
constexpr int Dd  = 960;
constexpr int RL  = 16;
constexpr int RD  = 32;
constexpr int LPp = 16;
constexpr int LHh = 384;
constexpr int DP  = 358;
constexpr int DH  = 154;

typedef float f32x4 __attribute__((ext_vector_type(4)));

struct EncParams {
    const float* X;     // (B, L, 960) embeddings
    const int*   mask;  // (B, L) contiguous prefix mask
    const float* A;     // (L, 16)
    const float* Bc;    // (960, 32)
    const float* Hc;    // (512, dmod)
    const float* W1;    // (dmod, dmod)
    const float* b1;    // (dmod)
    const float* g;     // (dmod)
    const float* beta;  // (dmod)
    const float* W2;    // (dmod, dmod)
    const float* b2;    // (dmod)
    int L;
    int dmod;
    int ooff;           // column offset in concat output
};

// =====================================================================
// Fully fused per-batch encoder. One block per (encoder, batch).
// Phase V: V[p][d] = sum_{l<len} A[l][p] * X[l][d]   (regs -> LDS, 61 KB)
//          X streamed once, nontemporal (protect params in L2).
// Phase U: U[p][r] = sum_d V[p][d] * Bc[d][r]        (16x32 -> Ush LDS)
// Phase z: z[j]    = sum_i U.flat[i] * Hc[i][j]      (-> zs, reuses Vs)
// Phase 1: h = relu((z@W1 + b1) * g/sqrt(1+eps) + beta)  (-> hs)
// Phase 2: out[b, ooff+c] = h@W2 + b2                (concat store)
// =====================================================================
__global__ __launch_bounds__(256)
void fused_kernel(EncParams H, EncParams P, float* __restrict__ out)
{
    const bool isH = ((int)blockIdx.x < Bn);
    const EncParams E = isH ? H : P;
    const int b = isH ? blockIdx.x : blockIdx.x - Bn;
    const int t = threadIdx.x;

    __shared__ float Vs[RL][Dd];    // 61440 B
    __shared__ float Ush[RL * RD];  // 2048 B
    __shared__ int   s_len;

    // ---- len_b = popcount of contiguous-prefix mask row ----
    if (t == 0) s_len = 0;
    __syncthreads();
    int loc = 0;
    for (int i = t; i < E.L; i += 256) loc += E.mask[(size_t)b * E.L + i];
    if (loc) atomicAdd(&s_len, loc);
    __syncthreads();
    const int len = s_len;

    // ---- Phase V: stream X, accumulate V in registers ----
    if (t < 240) {                       // 240 threads x 4 d-cols = 960
        float v[RL][4];
        #pragma unroll
        for (int p = 0; p < RL; ++p)
            #pragma unroll
            for (int q = 0; q < 4; ++q) v[p][q] = 0.f;

        const float* xrow = E.X + (size_t)b * E.L * Dd + 4 * t;
        #pragma unroll 2
        for (int l = 0; l < len; ++l) {
            f32x4 xv = __builtin_nontemporal_load((const f32x4*)xrow);
            xrow += Dd;
            float a[RL];
            *(f32x4*)&a[0]  = *(const f32x4*)(E.A + (size_t)l * RL + 0);
            *(f32x4*)&a[4]  = *(const f32x4*)(E.A + (size_t)l * RL + 4);
            *(f32x4*)&a[8]  = *(const f32x4*)(E.A + (size_t)l * RL + 8);
            *(f32x4*)&a[12] = *(const f32x4*)(E.A + (size_t)l * RL + 12);
            #pragma unroll
            for (int p = 0; p < RL; ++p) {
                v[p][0] = fmaf(a[p], xv[0], v[p][0]);
                v[p][1] = fmaf(a[p], xv[1], v[p][1]);
                v[p][2] = fmaf(a[p], xv[2], v[p][2]);
                v[p][3] = fmaf(a[p], xv[3], v[p][3]);
            }
        }
        #pragma unroll
        for (int p = 0; p < RL; ++p)
            *(f32x4*)&Vs[p][4 * t] = *(f32x4*)&v[p][0];
    }
    __syncthreads();

    // ---- Phase U: U = V * Bc  (b128 LDS broadcast + one Bc line/iter) ----
    {
        const int p = t >> 5, r = t & 31;
        float u0 = 0.f, u1 = 0.f;
        for (int dd = 0; dd < Dd; dd += 4) {
            f32x4 v0 = *(const f32x4*)&Vs[p][dd];
            f32x4 v1 = *(const f32x4*)&Vs[p + 8][dd];
            #pragma unroll
            for (int q = 0; q < 4; ++q) {
                float bc = E.Bc[(size_t)(dd + q) * RD + r];
                u0 = fmaf(v0[q], bc, u0);
                u1 = fmaf(v1[q], bc, u1);
            }
        }
        Ush[p * RD + r]       = u0;
        Ush[(p + 8) * RD + r] = u1;
    }
    __syncthreads();

    // ---- Phase z: z = vec(U) @ Hc  (zs reuses dead Vs space) ----
    float* zs = &Vs[0][0];
    float* hs = &Vs[0][0] + 512;
    for (int j = t; j < E.dmod; j += 256) {
        float acc = 0.f;
        #pragma unroll 8
        for (int i = 0; i < RL * RD; ++i)
            acc = fmaf(Ush[i], E.Hc[(size_t)i * E.dmod + j], acc);
        zs[j] = acc;
    }
    __syncthreads();

    // ---- Phase 1: h = relu(bn(z @ W1 + b1)) ----
    const float bscale = rsqrtf(1.f + 1e-5f);
    for (int c = t; c < E.dmod; c += 256) {
        float acc = E.b1[c];
        #pragma unroll 4
        for (int k = 0; k < E.dmod; ++k)
            acc = fmaf(zs[k], E.W1[(size_t)k * E.dmod + c], acc);
        acc = fmaf(acc, E.g[c] * bscale, E.beta[c]);
        hs[c] = fmaxf(acc, 0.f);
    }
    __syncthreads();

    // ---- Phase 2: out = h @ W2 + b2 (concat store) ----
    for (int c = t; c < E.dmod; c += 256) {
        float acc = E.b2[c];
        #pragma unroll 4
        for (int k = 0; k < E.dmod; ++k)
            acc = fmaf(hs[k], E.W2[(size_t)k * E.dmod + c], acc);
        out[(size_t)b * (DP + DH) + E.ooff + c] = acc;
    }
}

// =====================================================================
extern "C" void kernel_launch(void* const* d_in, const int* in_sizes, int n_in,
                              void* d_out, int out_size, void* d_ws, size_t ws_size,
                              hipStream_t stream)
{
    EncParams P, H;
    P.X    = (const float*)d_in[0];
    H.X    = (const float*)d_in[1];
    P.mask = (const int*)  d_in[2];
    H.mask = (const int*)  d_in[3];
    P.Bc   = (const float*)d_in[4];
    P.A    = (const float*)d_in[5];
    P.Hc   = (const float*)d_in[6];
    P.W1   = (const float*)d_in[7];
    P.b1   = (const float*)d_in[8];
    P.g    = (const float*)d_in[9];
    P.beta = (const float*)d_in[10];
    P.W2   = (const float*)d_in[11];
    P.b2   = (const float*)d_in[12];
    H.Bc   = (const float*)d_in[13];
    H.A    = (const float*)d_in[14];
    H.Hc   = (const float*)d_in[15];
    H.W1   = (const float*)d_in[16];
    H.b1   = (const float*)d_in[17];
    H.g    = (const float*)d_in[18];
    H.beta = (const float*)d_in[19];
    H.W2   = (const float*)d_in[20];
    H.b2   = (const float*)d_in[21];
    P.L = LPp;  P.dmod = DP;  P.ooff = 0;
    H.L = LHh;  H.dmod = DH;  H.ooff = DP;

    float* outp = (float*)d_out;

    // H blocks first (heavier streams start earliest)
    fused_kernel<<<dim3(2 * Bn), dim3(256), 0, stream>>>(H, P, outp);
}